// Round 19
// baseline (118.605 us; speedup 1.0000x reference)
//
#include <hip/hip_runtime.h>
#include <stdint.h>

// Problem constants: B=2, S=2048, E=1024, H=16, D=64, M = B*S = 4096
#define LOG2E 1.4426950408889634f
#define QSCALE (0.125f * LOG2E)   // fold 1/sqrt(64) and log2(e): softmax in exp2 domain

using u16 = unsigned short;
using u32 = unsigned int;

typedef __attribute__((ext_vector_type(8))) short short8;
typedef __attribute__((ext_vector_type(4))) float f32x4;
typedef __attribute__((ext_vector_type(16))) float f32x16;

__device__ __forceinline__ u16 f32_bf16(float f) {
  union { float f; u32 u; } v; v.f = f;
  u32 u = v.u;
  u += 0x7FFF + ((u >> 16) & 1);   // RNE
  return (u16)(u >> 16);
}

__device__ __forceinline__ float max3f(float a, float b, float c) {
  return fmaxf(fmaxf(a, b), c);    // clang fuses to v_max3_f32
}

__device__ __forceinline__ void gload_lds16(const void* g, void* l) {
  __builtin_amdgcn_global_load_lds(
      (const __attribute__((address_space(1))) u32*)(uintptr_t)g,
      (__attribute__((address_space(3))) u32*)(u32)(uintptr_t)l, 16, 0, 0);
}

// ---------------- pre-passes ----------------

__global__ __launch_bounds__(256) void cvt_f32_bf16(const float* __restrict__ in,
                                                    u16* __restrict__ out, int n4) {
  for (int i = blockIdx.x * blockDim.x + threadIdx.x; i < n4;
       i += gridDim.x * blockDim.x) {
    float4 v = ((const float4*)in)[i];
    union { u16 h[4]; uint2 u; } o;
    o.h[0] = f32_bf16(v.x); o.h[1] = f32_bf16(v.y);
    o.h[2] = f32_bf16(v.z); o.h[3] = f32_bf16(v.w);
    ((uint2*)out)[i] = o.u;
  }
}

// out[n][k] = bf16(in[k][n]);  in is [K][N] fp32 row-major
__global__ __launch_bounds__(256) void transpose_bf16(const float* __restrict__ in,
                                                      u16* __restrict__ out,
                                                      int K, int N) {
  __shared__ float t[32][33];
  const int n0 = blockIdx.x * 32, k0 = blockIdx.y * 32;
  const int tx = threadIdx.x, ty = threadIdx.y;
#pragma unroll
  for (int j = 0; j < 32; j += 8)
    t[ty + j][tx] = in[(size_t)(k0 + ty + j) * N + n0 + tx];
  __syncthreads();
#pragma unroll
  for (int j = 0; j < 32; j += 8)
    out[(size_t)(n0 + ty + j) * K + k0 + tx] = f32_bf16(t[tx][ty + j]);
}

// ---------------- GEMM: C = A[M,K] * Bt[N,K]^T + bias, 128x128, 8 waves, RING-4 ----------------
// R18's 8-wave skeleton (validated) with 4-slot LDS ring (64KB): stage t+3 at bottom of
// step t -> prefetch slack = 2 full steps (~2300cy > worst-case latency). 2 blocks/CU x
// 8 waves = 16 waves/CU. vmcnt: outstanding {t,t+1,t+2} = 6 loads -> wait 4 (tail 2->0).
// Race: slot (t+3)&3 == (t-1)&3, readers finished two barriers ago.
// Both-sides XOR swizzle (0 conflicts, validated R7-R18).
// MODE 0 (QKV): 1D grid 768, XCD bn-slab swizzle (B slab 0.75MB L2-hot); Q/K/V^T scatter.
// MODE 1 (proj): 2D grid (8,32); fp32 + bias.
template <int MODE>
__global__ __launch_bounds__(512, 4) void gemm_r4(
    const u16* __restrict__ A, const u16* __restrict__ Bt,
    const float* __restrict__ bias,
    u16* __restrict__ qb, u16* __restrict__ kb, u16* __restrict__ vtb,
    float* __restrict__ fout) {
  __shared__ u16 lA[4][4096];   // 4 x 8KB: 64 row-pairs x 8 swizzled 16B slots
  __shared__ u16 lB[4][4096];
  const int tid = threadIdx.x;
  const int w = tid >> 6, l = tid & 63;
  const int l15 = l & 15, l4 = l >> 4;
  const int wrow = w >> 1, wcol = w & 1;   // wave tile: rows wrow*32..+32, cols wcol*64..+64
  int bm, bn;
  if (MODE == 0) {
    // bijective XCD slab map: XCD x owns bn in [3x, 3x+3) x all 32 bm
    const int bid = blockIdx.x;            // 0..767
    const int xcd = bid & 7, s = bid >> 3; // 96 blocks per XCD
    bn = xcd * 3 + (s % 3);
    bm = s / 3;
  } else {
    bm = blockIdx.y; bn = blockIdx.x;
  }
  const size_t m0 = (size_t)bm * 128, n0 = (size_t)bn * 128;

  f32x4 acc[2][4] = {};

  // staging: thread tid owns A-chunk tid and B-chunk tid; inverse-swizzled row (rule #21)
  const int pair0 = tid >> 3, s80 = tid & 7;
  const int us8 = s80 ^ (pair0 & 7);
  const int grow = 2 * pair0 + (us8 >> 2);
  const int kslot = us8 & 3;
  const u16* gA = A + (m0 + grow) * 1024 + kslot * 8;
  const u16* gB = Bt + (n0 + grow) * 1024 + kslot * 8;

  auto stage = [&](int s, int t) {
    const int k0 = t * 32;
    gload_lds16(gA + k0, lA[s] + w * 512);
    gload_lds16(gB + k0, lB[s] + w * 512);
  };

  // prologue: 3 tiles in flight (6 loads/wave)
  stage(0, 0);
  stage(1, 1);
  stage(2, 2);

  for (int t = 0; t < 32; ++t) {
    const int buf = t & 3;
    if (t <= 29)      asm volatile("s_waitcnt vmcnt(4)" ::: "memory");
    else if (t == 30) asm volatile("s_waitcnt vmcnt(2)" ::: "memory");
    else              asm volatile("s_waitcnt vmcnt(0)" ::: "memory");
    __builtin_amdgcn_s_barrier();
    __builtin_amdgcn_sched_barrier(0);
    short8 af[2], bf[4];
#pragma unroll
    for (int mI = 0; mI < 2; ++mI) {
      const int row = wrow * 32 + mI * 16 + l15;
      const int pr = row >> 1;
      const int s8 = (((row & 1) << 2) | l4) ^ (pr & 7);
      af[mI] = *(const short8*)((const char*)lA[buf] + pr * 128 + s8 * 16);
    }
#pragma unroll
    for (int n = 0; n < 4; ++n) {
      const int row = wcol * 64 + n * 16 + l15;
      const int pr = row >> 1;
      const int s8 = (((row & 1) << 2) | l4) ^ (pr & 7);
      bf[n] = *(const short8*)((const char*)lB[buf] + pr * 128 + s8 * 16);
    }
    __builtin_amdgcn_s_setprio(1);
#pragma unroll
    for (int mI = 0; mI < 2; ++mI)
#pragma unroll
      for (int n = 0; n < 4; ++n)
        acc[mI][n] = __builtin_amdgcn_mfma_f32_16x16x32_bf16(af[mI], bf[n], acc[mI][n], 0, 0, 0);
    __builtin_amdgcn_s_setprio(0);
    __builtin_amdgcn_s_barrier();
    if (t + 3 < 32) stage((t + 3) & 3, t + 3);
  }

  if (MODE == 0) {
#pragma unroll
    for (int mI = 0; mI < 2; ++mI) {
      const int row = (int)m0 + wrow * 32 + mI * 16 + (l4 << 2);
      const int b = row >> 11, s = row & 2047;
#pragma unroll
      for (int n = 0; n < 4; ++n) {
        const int col = (int)n0 + wcol * 64 + n * 16 + l15;
        const int part = col >> 10;
        const int h = (col & 1023) >> 6, d = col & 63;
        const float bv = bias[col];
        const size_t bh = (size_t)(b * 16 + h);
#pragma unroll
        for (int r = 0; r < 4; ++r) {
          const float v = acc[mI][n][r] + bv;
          const int ss = s + r;
          if (part == 0)
            qb[(bh * 2048 + ss) * 64 + d] = f32_bf16(v * QSCALE);
          else if (part == 1)
            kb[(bh * 2048 + ss) * 64 + d] = f32_bf16(v);
          else
            vtb[(bh * 64 + d) * 2048 + ss] = f32_bf16(v);  // V transposed
        }
      }
    }
  } else {
#pragma unroll
    for (int mI = 0; mI < 2; ++mI) {
      const size_t row = m0 + wrow * 32 + mI * 16 + (l4 << 2);
#pragma unroll
      for (int n = 0; n < 4; ++n) {
        const size_t col = n0 + wcol * 64 + n * 16 + l15;
        const float bv = bias[col];
#pragma unroll
        for (int r = 0; r < 4; ++r)
          fout[(row + r) * 1024 + col] = acc[mI][n][r] + bv;
      }
    }
  }
}

// ---------------- causal flash attention: kv-split-2, 8 waves, LDS-shared ----------------
// R15/R16/R18's attn_fwd10 VERBATIM (validated).
__global__ __launch_bounds__(512) void attn_fwd10(const u16* __restrict__ Qb,
                                                  const u16* __restrict__ Kb,
                                                  const u16* __restrict__ Vt,
                                                  u16* __restrict__ AO) {
  __shared__ u16 lK[2][2][4096];   // [group][buf][64 rows x 64 elems]
  __shared__ u16 lV[2][2][4096];
  const int tid = threadIdx.x;
  const int l = tid & 63, w = tid >> 6;    // w in 0..7
  const int g = w >> 2, wl = w & 3;        // group, wave-in-group
  const int lq = l & 31, hi = l >> 5;
  const int bid = blockIdx.x;
  const int xcd = bid & 7, idx = bid >> 3;
  const int bh = xcd * 4 + (idx & 3);
  const int qb = 15 - (idx >> 2);          // q-block 0..15 (128 rows each), heavy first
  const int q = qb * 128 + wl * 32 + lq;
  const int cdiag = 2 * qb + (wl >> 1);    // absolute chunk idx of this wave's diagonal
  const int NC = qb + 1;                   // chunks per group (group g: c = 2i+g)

  const u16* Qh = Qb + (size_t)bh * 131072;
  const u16* Kh = Kb + (size_t)bh * 131072;
  const u16* Vh = Vt + (size_t)bh * 131072;

  short8 qf[4];
#pragma unroll
  for (int kk = 0; kk < 4; ++kk)
    qf[kk] = *(const short8*)&Qh[(size_t)q * 64 + kk * 16 + hi * 8];

  f32x16 oA = {}, oB = {};
  float m = -3.0e38f, lsum = 0.f;

  const int srow = l >> 3, sslot = l & 7;
  const int swz = ((sslot ^ srow) << 3);
  const u16* kbase = Kh + (16 * wl + srow) * 64 + swz;
  const u16* vbase = Vh + (size_t)(16 * wl + srow) * 2048 + swz;
  char* lKg = (char*)&lK[g][0][0] + 2 * wl * 1024;
  char* lVg = (char*)&lV[g][0][0] + 2 * wl * 1024;

  auto stage = [&](int buf, int cabs) {
    const u16* ks = kbase + cabs * 4096;
    const u16* vs = vbase + cabs * 64;
    char* kd = lKg + buf * 8192;
    char* vd = lVg + buf * 8192;
    gload_lds16(ks, kd);
    gload_lds16(ks + 512, kd + 1024);
    gload_lds16(vs, vd);
    gload_lds16(vs + 16384, vd + 1024);
  };

  const int swsl = (lq & 7);

  auto pack16 = [&](const f32x16& st, short8& lo, short8& hi8) {
    u32 pk[8];
#pragma unroll
    for (int t2 = 0; t2 < 8; ++t2)
      asm("v_cvt_pk_bf16_f32 %0, %1, %2" : "=v"(pk[t2]) : "v"(st[2 * t2]), "v"(st[2 * t2 + 1]));
    u32 a0 = pk[0], a1 = pk[2]; asm("v_permlane32_swap_b32 %0, %1" : "+v"(a0), "+v"(a1));
    u32 a2 = pk[1], a3 = pk[3]; asm("v_permlane32_swap_b32 %0, %1" : "+v"(a2), "+v"(a3));
    u32 c0 = pk[4], c1 = pk[6]; asm("v_permlane32_swap_b32 %0, %1" : "+v"(c0), "+v"(c1));
    u32 c2 = pk[5], c3 = pk[7]; asm("v_permlane32_swap_b32 %0, %1" : "+v"(c2), "+v"(c3));
    union { u32 u[4]; short8 s; } f0, f1;
    f0.u[0] = a0; f0.u[1] = a2; f0.u[2] = a1; f0.u[3] = a3;
    f1.u[0] = c0; f1.u[1] = c2; f1.u[2] = c1; f1.u[3] = c3;
    lo = f0.s; hi8 = f1.s;
  };

  auto body64 = [&](int buf, bool mask2) {
    const char* kb = (const char*)&lK[g][buf][0] + lq * 128;
    const char* vb = (const char*)&lV[g][buf][0] + lq * 128;
    short8 kf0[4], kf1[4];
#pragma unroll
    for (int kk = 0; kk < 4; ++kk) {
      const int sl = ((2 * kk + hi) ^ swsl) << 4;
      kf0[kk] = *(const short8*)(kb + sl);
      kf1[kk] = *(const short8*)(kb + 4096 + sl);
    }
    f32x16 st0 = {}, st1 = {};
    __builtin_amdgcn_s_setprio(1);
#pragma unroll
    for (int kk = 0; kk < 4; ++kk)
      st0 = __builtin_amdgcn_mfma_f32_32x32x16_bf16(kf0[kk], qf[kk], st0, 0, 0, 0);
#pragma unroll
    for (int kk = 0; kk < 4; ++kk)
      st1 = __builtin_amdgcn_mfma_f32_32x32x16_bf16(kf1[kk], qf[kk], st1, 0, 0, 0);
    __builtin_amdgcn_s_setprio(0);

    short8 vfA[4], vfB[4];
#pragma unroll
    for (int ks = 0; ks < 4; ++ks) {
      const int sl = ((2 * ks + hi) ^ swsl) << 4;
      vfA[ks] = *(const short8*)(vb + sl);
      vfB[ks] = *(const short8*)(vb + 4096 + sl);
    }

    if (mask2) {
      const int qm = lq - hi * 4;
#pragma unroll
      for (int r = 0; r < 16; ++r) {
        const int t = (r & 3) + 8 * (r >> 2);
        if (t > qm) st1[r] = -3.0e38f;
      }
    }

    float a0 = max3f(st0[0], st0[1], st0[2]);
    float a1 = max3f(st0[3], st0[4], st0[5]);
    float a2 = max3f(st0[6], st0[7], st0[8]);
    float a3 = max3f(st0[9], st0[10], st0[11]);
    float a4 = max3f(st0[12], st0[13], st0[14]);
    float a5 = max3f(st0[15], st1[0], st1[1]);
    float a6 = max3f(st1[2], st1[3], st1[4]);
    float a7 = max3f(st1[5], st1[6], st1[7]);
    float a8 = max3f(st1[8], st1[9], st1[10]);
    float a9 = max3f(st1[11], st1[12], st1[13]);
    float a10 = fmaxf(st1[14], st1[15]);
    float b0 = max3f(a0, a1, a2);
    float b1 = max3f(a3, a4, a5);
    float b2 = max3f(a6, a7, a8);
    float b3 = max3f(a9, a10, b0);
    float pm = max3f(b1, b2, b3);
    pm = fmaxf(pm, __shfl_xor(pm, 32));

    if (!__all(pm <= m + 8.0f)) {        // defer-max (T13)
      const float mn = fmaxf(m, pm);
      const float alpha = __builtin_amdgcn_exp2f(m - mn);
      lsum *= alpha;
#pragma unroll
      for (int r = 0; r < 16; ++r) { oA[r] *= alpha; oB[r] *= alpha; }
      m = mn;
    }

#pragma unroll
    for (int r = 0; r < 16; ++r) st0[r] = __builtin_amdgcn_exp2f(st0[r] - m);
#pragma unroll
    for (int r = 0; r < 16; ++r) st1[r] = __builtin_amdgcn_exp2f(st1[r] - m);

    float s0 = (st0[0] + st0[1]) + (st0[2] + st0[3]);
    float s1 = (st0[4] + st0[5]) + (st0[6] + st0[7]);
    float s2 = (st0[8] + st0[9]) + (st0[10] + st0[11]);
    float s3 = (st0[12] + st0[13]) + (st0[14] + st0[15]);
    float s4 = (st1[0] + st1[1]) + (st1[2] + st1[3]);
    float s5 = (st1[4] + st1[5]) + (st1[6] + st1[7]);
    float s6 = (st1[8] + st1[9]) + (st1[10] + st1[11]);
    float s7 = (st1[12] + st1[13]) + (st1[14] + st1[15]);
    float rs = ((s0 + s1) + (s2 + s3)) + ((s4 + s5) + (s6 + s7));
    rs += __shfl_xor(rs, 32);
    lsum += rs;

    short8 pf0, pf1, pf2, pf3;
    pack16(st0, pf0, pf1);
    pack16(st1, pf2, pf3);

    __builtin_amdgcn_s_setprio(1);
    oA = __builtin_amdgcn_mfma_f32_32x32x16_bf16(vfA[0], pf0, oA, 0, 0, 0);
    oA = __builtin_amdgcn_mfma_f32_32x32x16_bf16(vfA[1], pf1, oA, 0, 0, 0);
    oA = __builtin_amdgcn_mfma_f32_32x32x16_bf16(vfA[2], pf2, oA, 0, 0, 0);
    oA = __builtin_amdgcn_mfma_f32_32x32x16_bf16(vfA[3], pf3, oA, 0, 0, 0);
    oB = __builtin_amdgcn_mfma_f32_32x32x16_bf16(vfB[0], pf0, oB, 0, 0, 0);
    oB = __builtin_amdgcn_mfma_f32_32x32x16_bf16(vfB[1], pf1, oB, 0, 0, 0);
    oB = __builtin_amdgcn_mfma_f32_32x32x16_bf16(vfB[2], pf2, oB, 0, 0, 0);
    oB = __builtin_amdgcn_mfma_f32_32x32x16_bf16(vfB[3], pf3, oB, 0, 0, 0);
    __builtin_amdgcn_s_setprio(0);
  };

  auto body32m = [&](int buf) {
    const char* kb = (const char*)&lK[g][buf][0] + lq * 128;
    const char* vb = (const char*)&lV[g][buf][0] + lq * 128;
    short8 kf0[4];
#pragma unroll
    for (int kk = 0; kk < 4; ++kk)
      kf0[kk] = *(const short8*)(kb + (((2 * kk + hi) ^ swsl) << 4));
    f32x16 st0 = {};
    __builtin_amdgcn_s_setprio(1);
#pragma unroll
    for (int kk = 0; kk < 4; ++kk)
      st0 = __builtin_amdgcn_mfma_f32_32x32x16_bf16(kf0[kk], qf[kk], st0, 0, 0, 0);
    __builtin_amdgcn_s_setprio(0);

    short8 vfA[2], vfB[2];
#pragma unroll
    for (int ks = 0; ks < 2; ++ks) {
      const int sl = ((2 * ks + hi) ^ swsl) << 4;
      vfA[ks] = *(const short8*)(vb + sl);
      vfB[ks] = *(const short8*)(vb + 4096 + sl);
    }

    const int qm = lq - hi * 4;
#pragma unroll
    for (int r = 0; r < 16; ++r) {
      const int t = (r & 3) + 8 * (r >> 2);
      if (t > qm) st0[r] = -3.0e38f;
    }
    float a0 = max3f(st0[0], st0[1], st0[2]);
    float a1 = max3f(st0[3], st0[4], st0[5]);
    float a2 = max3f(st0[6], st0[7], st0[8]);
    float a3 = max3f(st0[9], st0[10], st0[11]);
    float a4 = max3f(st0[12], st0[13], st0[14]);
    float b0 = max3f(a0, a1, a2);
    float b1 = max3f(a3, a4, st0[15]);
    float pm = fmaxf(b0, b1);
    pm = fmaxf(pm, __shfl_xor(pm, 32));
    if (!__all(pm <= m + 8.0f)) {
      const float mn = fmaxf(m, pm);
      const float alpha = __builtin_amdgcn_exp2f(m - mn);
      lsum *= alpha;
#pragma unroll
      for (int r = 0; r < 16; ++r) { oA[r] *= alpha; oB[r] *= alpha; }
      m = mn;
    }
#pragma unroll
    for (int r = 0; r < 16; ++r) st0[r] = __builtin_amdgcn_exp2f(st0[r] - m);
    float s0 = (st0[0] + st0[1]) + (st0[2] + st0[3]);
    float s1 = (st0[4] + st0[5]) + (st0[6] + st0[7]);
    float s2 = (st0[8] + st0[9]) + (st0[10] + st0[11]);
    float s3 = (st0[12] + st0[13]) + (st0[14] + st0[15]);
    float rs = (s0 + s1) + (s2 + s3);
    rs += __shfl_xor(rs, 32);
    lsum += rs;

    short8 pf0, pf1;
    pack16(st0, pf0, pf1);
    __builtin_amdgcn_s_setprio(1);
    oA = __builtin_amdgcn_mfma_f32_32x32x16_bf16(vfA[0], pf0, oA, 0, 0, 0);
    oA = __builtin_amdgcn_mfma_f32_32x32x16_bf16(vfA[1], pf1, oA, 0, 0, 0);
    oB = __builtin_amdgcn_mfma_f32_32x32x16_bf16(vfB[0], pf0, oB, 0, 0, 0);
    oB = __builtin_amdgcn_mfma_f32_32x32x16_bf16(vfB[1], pf1, oB, 0, 0, 0);
    __builtin_amdgcn_s_setprio(0);
  };

  // per-group counted-vmcnt schedule (validated R15)
  stage(0, g);
  if (NC > 1) stage(1, 2 + g);
  for (int i = 0; i < NC; ++i) {
    const int cabs = 2 * i + g;
    const int buf = i & 1;
    if (i + 1 < NC) asm volatile("s_waitcnt vmcnt(4)" ::: "memory");
    else            asm volatile("s_waitcnt vmcnt(0)" ::: "memory");
    __builtin_amdgcn_s_barrier();
    __builtin_amdgcn_sched_barrier(0);
    if (cabs < cdiag) body64(buf, false);
    else if (cabs == cdiag) { if (wl & 1) body64(buf, true); else body32m(buf); }
    __builtin_amdgcn_s_barrier();
    if (i + 2 < NC) stage(buf, 2 * (i + 2) + g);
  }

  // merge: group 1 deposits (O, m, l) in reused LDS; group 0 merges and stores.
  float* mergeO  = (float*)&lK[0][0][0];   // [r 0..31][wave 0..3][lane] = 32KB
  float* mergeML = (float*)&lV[0][0][0];   // [0..511] m, [512..1023] lsum
  if (g == 1) {
#pragma unroll
    for (int r = 0; r < 16; ++r) {
      mergeO[r * 256 + wl * 64 + l] = oA[r];
      mergeO[(16 + r) * 256 + wl * 64 + l] = oB[r];
    }
    mergeML[wl * 64 + l] = m;
    mergeML[512 + wl * 64 + l] = lsum;
  }
  __syncthreads();
  if (g == 0) {
    const float m1 = mergeML[wl * 64 + l];
    const float l1 = mergeML[512 + wl * 64 + l];
    const float M = fmaxf(m, m1);
    const float sc0 = __builtin_amdgcn_exp2f(m - M);
    const float sc1 = __builtin_amdgcn_exp2f(m1 - M);
    const float L = lsum * sc0 + l1 * sc1;
    const float rl = __builtin_amdgcn_rcpf(L);
    const float a0 = sc0 * rl, a1 = sc1 * rl;
    const int b = bh >> 4, h = bh & 15;
    u16* orow = AO + ((size_t)(b * 2048 + q)) * 1024 + h * 64;
#pragma unroll
    for (int g4 = 0; g4 < 4; ++g4) {
      float e[4], f[4];
#pragma unroll
      for (int t = 0; t < 4; ++t) {
        const int r = 4 * g4 + t;
        e[t] = oA[r] * a0 + mergeO[r * 256 + wl * 64 + l] * a1;
        f[t] = oB[r] * a0 + mergeO[(16 + r) * 256 + wl * 64 + l] * a1;
      }
      u32 w0, w1, w2, w3;
      asm("v_cvt_pk_bf16_f32 %0, %1, %2" : "=v"(w0) : "v"(e[0]), "v"(e[1]));
      asm("v_cvt_pk_bf16_f32 %0, %1, %2" : "=v"(w1) : "v"(e[2]), "v"(e[3]));
      asm("v_cvt_pk_bf16_f32 %0, %1, %2" : "=v"(w2) : "v"(f[0]), "v"(f[1]));
      asm("v_cvt_pk_bf16_f32 %0, %1, %2" : "=v"(w3) : "v"(f[2]), "v"(f[3]));
      uint2 uA; uA.x = w0; uA.y = w1;
      uint2 uB; uB.x = w2; uB.y = w3;
      *(uint2*)&orow[8 * g4 + 4 * hi] = uA;        // d = 8*g4+4hi .. +3
      *(uint2*)&orow[32 + 8 * g4 + 4 * hi] = uB;   // d+32
    }
  }
}

// ---------------- launch ----------------

extern "C" void kernel_launch(void* const* d_in, const int* in_sizes, int n_in,
                              void* d_out, int out_size, void* d_ws, size_t ws_size,
                              hipStream_t stream) {
  const float* hs = (const float*)d_in[0];
  const float* w1 = (const float*)d_in[1];
  const float* b1 = (const float*)d_in[2];
  const float* w2 = (const float*)d_in[3];
  const float* b2 = (const float*)d_in[4];
  float* out = (float*)d_out;

  char* ws = (char*)d_ws;
  u16* Xb  = (u16*)(ws);                    // [4096][1024] bf16   (8 MB)
  u16* W1t = (u16*)(ws + (8ull  << 20));    // [3072][1024] bf16   (6 MB)
  u16* W2t = (u16*)(ws + (14ull << 20));    // [1024][1024] bf16   (2 MB)
  u16* Qb  = (u16*)(ws + (16ull << 20));    // [B,H,S,D] bf16      (8 MB)
  u16* Kb  = (u16*)(ws + (24ull << 20));    // [B,H,S,D] bf16      (8 MB)
  u16* Vtb = (u16*)(ws + (32ull << 20));    // [B,H,D,S] bf16      (8 MB)
  u16* AO  = (u16*)(ws + (40ull << 20));    // [4096][1024] bf16   (8 MB)

  cvt_f32_bf16<<<dim3(2048), dim3(256), 0, stream>>>(hs, Xb, 4096 * 1024 / 4);
  transpose_bf16<<<dim3(96, 32), dim3(32, 8), 0, stream>>>(w1, W1t, 1024, 3072);
  transpose_bf16<<<dim3(32, 32), dim3(32, 8), 0, stream>>>(w2, W2t, 1024, 1024);
  gemm_r4<0><<<dim3(768), dim3(512), 0, stream>>>(Xb, W1t, b1, Qb, Kb, Vtb, nullptr);
  attn_fwd10<<<dim3(512), dim3(512), 0, stream>>>(Qb, Kb, Vtb, AO);
  gemm_r4<1><<<dim3(8, 32), dim3(512), 0, stream>>>(AO, W2t, b2, nullptr, nullptr, nullptr, out);
}

// Round 20
// 101.411 us; speedup vs baseline: 1.1695x; 1.1695x over previous
//
#include <hip/hip_runtime.h>
#include <stdint.h>

// Problem constants: B=2, S=2048, E=1024, H=16, D=64, M = B*S = 4096
#define LOG2E 1.4426950408889634f
#define QSCALE (0.125f * LOG2E)   // fold 1/sqrt(64) and log2(e): softmax in exp2 domain

using u16 = unsigned short;
using u32 = unsigned int;

typedef __attribute__((ext_vector_type(8))) short short8;
typedef __attribute__((ext_vector_type(4))) float f32x4;
typedef __attribute__((ext_vector_type(16))) float f32x16;

__device__ __forceinline__ u16 f32_bf16(float f) {
  union { float f; u32 u; } v; v.f = f;
  u32 u = v.u;
  u += 0x7FFF + ((u >> 16) & 1);   // RNE
  return (u16)(u >> 16);
}

__device__ __forceinline__ float max3f(float a, float b, float c) {
  return fmaxf(fmaxf(a, b), c);    // clang fuses to v_max3_f32
}

__device__ __forceinline__ void gload_lds16(const void* g, void* l) {
  __builtin_amdgcn_global_load_lds(
      (const __attribute__((address_space(1))) u32*)(uintptr_t)g,
      (__attribute__((address_space(3))) u32*)(u32)(uintptr_t)l, 16, 0, 0);
}

// ---------------- fused pre-pass: cvt(X) + transpose(W1) + transpose(W2) ----------------
// One launch, blockIdx-dispatched roles (bodies identical to the R0-validated kernels).
// bid in [0,2048):    cvt 4096x1024 f32 -> bf16 (float4-wide, 2 chunks/thread)
// bid in [2048,5120): W1t[n][k] = bf16(w1[k][n])   (K=1024, N=3072; 32x32 tile)
// bid in [5120,6144): W2t[n][k] = bf16(w2[k][n])   (K=1024, N=1024; 32x32 tile)
__global__ __launch_bounds__(256) void prepass(const float* __restrict__ hs,
                                               u16* __restrict__ Xb,
                                               const float* __restrict__ w1,
                                               u16* __restrict__ W1t,
                                               const float* __restrict__ w2,
                                               u16* __restrict__ W2t) {
  __shared__ float t[32][33];
  const int bid = blockIdx.x;
  const int tid = threadIdx.x;
  if (bid < 2048) {
    const int base = bid * 256 + tid;
#pragma unroll
    for (int it = 0; it < 2; ++it) {
      const int i = base + it * 524288;   // 2 x 524288 = 1048576 float4 = 4096*1024
      float4 v = ((const float4*)hs)[i];
      union { u16 h[4]; uint2 u; } o;
      o.h[0] = f32_bf16(v.x); o.h[1] = f32_bf16(v.y);
      o.h[2] = f32_bf16(v.z); o.h[3] = f32_bf16(v.w);
      ((uint2*)Xb)[i] = o.u;
    }
    return;
  }
  const float* in;
  u16* out;
  int N, n0, k0;
  if (bid < 5120) {
    const int idx = bid - 2048;           // 0..3071
    in = w1; out = W1t; N = 3072;
    n0 = (idx % 96) * 32; k0 = (idx / 96) * 32;
  } else {
    const int idx = bid - 5120;           // 0..1023
    in = w2; out = W2t; N = 1024;
    n0 = (idx & 31) * 32; k0 = (idx >> 5) * 32;
  }
  const int tx = tid & 31, ty = tid >> 5;
#pragma unroll
  for (int j = 0; j < 32; j += 8)
    t[ty + j][tx] = in[(size_t)(k0 + ty + j) * N + n0 + tx];
  __syncthreads();
#pragma unroll
  for (int j = 0; j < 32; j += 8)
    out[(size_t)(n0 + ty + j) * 1024 + k0 + tx] = f32_bf16(t[tx][ty + j]);
}

// ---------------- GEMM: C = A[M,K] * Bt[N,K]^T + bias, 128x128 tile, 8 WAVES ----------------
// R18 VERBATIM (best measured: QKV 46.3 us, 50% occupancy). 128^2 tile, grid 768 =
// 3 blocks/CU, 8 waves/block -> 24 waves/CU. Wave tile 32x64 (af[2]+bf[4]).
// db LDS (32KB) + 2-barrier + counted vmcnt(2) schedule (R11-validated).
// Both-sides XOR swizzle (0 conflicts, validated R7-R18).
// MODE 0: QKV epilogue -> scatter Q*QSCALE, K, V^T (bf16). MODE 1: fp32 + bias.
template <int MODE>
__global__ __launch_bounds__(512, 6) void gemm8w(
    const u16* __restrict__ A, const u16* __restrict__ Bt,
    const float* __restrict__ bias,
    u16* __restrict__ qb, u16* __restrict__ kb, u16* __restrict__ vtb,
    float* __restrict__ fout) {
  __shared__ u16 lA[2][4096];   // 2 x 8KB: 64 row-pairs x 8 swizzled 16B slots
  __shared__ u16 lB[2][4096];
  const int tid = threadIdx.x;
  const int w = tid >> 6, l = tid & 63;
  const int l15 = l & 15, l4 = l >> 4;
  const int wrow = w >> 1, wcol = w & 1;   // wave tile: rows wrow*32..+32, cols wcol*64..+64
  const int bm = blockIdx.y, bn = blockIdx.x;
  const size_t m0 = (size_t)bm * 128, n0 = (size_t)bn * 128;

  f32x4 acc[2][4] = {};

  // staging: thread tid owns A-chunk tid and B-chunk tid (512 chunks each);
  // inverse-swizzled global row (rule #21)
  const int pair0 = tid >> 3, s80 = tid & 7;
  const int us8 = s80 ^ (pair0 & 7);
  const int grow = 2 * pair0 + (us8 >> 2);
  const int kslot = us8 & 3;
  const u16* gA = A + (m0 + grow) * 1024 + kslot * 8;
  const u16* gB = Bt + (n0 + grow) * 1024 + kslot * 8;

  auto stage = [&](int buf, int t) {
    const int k0 = t * 32;
    gload_lds16(gA + k0, lA[buf] + w * 512);
    gload_lds16(gB + k0, lB[buf] + w * 512);
  };

  stage(0, 0);
  stage(1, 1);

  for (int t = 0; t < 32; ++t) {
    const int buf = t & 1;
    if (t == 31) asm volatile("s_waitcnt vmcnt(0)" ::: "memory");
    else         asm volatile("s_waitcnt vmcnt(2)" ::: "memory");
    __builtin_amdgcn_s_barrier();
    __builtin_amdgcn_sched_barrier(0);
    short8 af[2], bf[4];
#pragma unroll
    for (int mI = 0; mI < 2; ++mI) {
      const int row = wrow * 32 + mI * 16 + l15;
      const int pr = row >> 1;
      const int s8 = (((row & 1) << 2) | l4) ^ (pr & 7);
      af[mI] = *(const short8*)((const char*)lA[buf] + pr * 128 + s8 * 16);
    }
#pragma unroll
    for (int n = 0; n < 4; ++n) {
      const int row = wcol * 64 + n * 16 + l15;
      const int pr = row >> 1;
      const int s8 = (((row & 1) << 2) | l4) ^ (pr & 7);
      bf[n] = *(const short8*)((const char*)lB[buf] + pr * 128 + s8 * 16);
    }
    __builtin_amdgcn_s_setprio(1);
#pragma unroll
    for (int mI = 0; mI < 2; ++mI)
#pragma unroll
      for (int n = 0; n < 4; ++n)
        acc[mI][n] = __builtin_amdgcn_mfma_f32_16x16x32_bf16(af[mI], bf[n], acc[mI][n], 0, 0, 0);
    __builtin_amdgcn_s_setprio(0);
    __builtin_amdgcn_s_barrier();
    if (t + 2 < 32) stage(buf, t + 2);
  }

  if (MODE == 0) {
#pragma unroll
    for (int mI = 0; mI < 2; ++mI) {
      const int row = (int)m0 + wrow * 32 + mI * 16 + (l4 << 2);
      const int b = row >> 11, s = row & 2047;
#pragma unroll
      for (int n = 0; n < 4; ++n) {
        const int col = (int)n0 + wcol * 64 + n * 16 + l15;
        const int part = col >> 10;
        const int h = (col & 1023) >> 6, d = col & 63;
        const float bv = bias[col];
        const size_t bh = (size_t)(b * 16 + h);
#pragma unroll
        for (int r = 0; r < 4; ++r) {
          const float v = acc[mI][n][r] + bv;
          const int ss = s + r;
          if (part == 0)
            qb[(bh * 2048 + ss) * 64 + d] = f32_bf16(v * QSCALE);
          else if (part == 1)
            kb[(bh * 2048 + ss) * 64 + d] = f32_bf16(v);
          else
            vtb[(bh * 64 + d) * 2048 + ss] = f32_bf16(v);  // V transposed
        }
      }
    }
  } else {
#pragma unroll
    for (int mI = 0; mI < 2; ++mI) {
      const size_t row = m0 + wrow * 32 + mI * 16 + (l4 << 2);
#pragma unroll
      for (int n = 0; n < 4; ++n) {
        const size_t col = n0 + wcol * 64 + n * 16 + l15;
        const float bv = bias[col];
#pragma unroll
        for (int r = 0; r < 4; ++r)
          fout[(row + r) * 1024 + col] = acc[mI][n][r] + bv;
      }
    }
  }
}

// ---------------- causal flash attention: kv-split-2, 8 waves, LDS-shared ----------------
// R15/R16/R18's attn_fwd10 VERBATIM (validated).
__global__ __launch_bounds__(512) void attn_fwd10(const u16* __restrict__ Qb,
                                                  const u16* __restrict__ Kb,
                                                  const u16* __restrict__ Vt,
                                                  u16* __restrict__ AO) {
  __shared__ u16 lK[2][2][4096];   // [group][buf][64 rows x 64 elems]
  __shared__ u16 lV[2][2][4096];
  const int tid = threadIdx.x;
  const int l = tid & 63, w = tid >> 6;    // w in 0..7
  const int g = w >> 2, wl = w & 3;        // group, wave-in-group
  const int lq = l & 31, hi = l >> 5;
  const int bid = blockIdx.x;
  const int xcd = bid & 7, idx = bid >> 3;
  const int bh = xcd * 4 + (idx & 3);
  const int qb = 15 - (idx >> 2);          // q-block 0..15 (128 rows each), heavy first
  const int q = qb * 128 + wl * 32 + lq;
  const int cdiag = 2 * qb + (wl >> 1);    // absolute chunk idx of this wave's diagonal
  const int NC = qb + 1;                   // chunks per group (group g: c = 2i+g)

  const u16* Qh = Qb + (size_t)bh * 131072;
  const u16* Kh = Kb + (size_t)bh * 131072;
  const u16* Vh = Vt + (size_t)bh * 131072;

  short8 qf[4];
#pragma unroll
  for (int kk = 0; kk < 4; ++kk)
    qf[kk] = *(const short8*)&Qh[(size_t)q * 64 + kk * 16 + hi * 8];

  f32x16 oA = {}, oB = {};
  float m = -3.0e38f, lsum = 0.f;

  const int srow = l >> 3, sslot = l & 7;
  const int swz = ((sslot ^ srow) << 3);
  const u16* kbase = Kh + (16 * wl + srow) * 64 + swz;
  const u16* vbase = Vh + (size_t)(16 * wl + srow) * 2048 + swz;
  char* lKg = (char*)&lK[g][0][0] + 2 * wl * 1024;
  char* lVg = (char*)&lV[g][0][0] + 2 * wl * 1024;

  auto stage = [&](int buf, int cabs) {
    const u16* ks = kbase + cabs * 4096;
    const u16* vs = vbase + cabs * 64;
    char* kd = lKg + buf * 8192;
    char* vd = lVg + buf * 8192;
    gload_lds16(ks, kd);
    gload_lds16(ks + 512, kd + 1024);
    gload_lds16(vs, vd);
    gload_lds16(vs + 16384, vd + 1024);
  };

  const int swsl = (lq & 7);

  auto pack16 = [&](const f32x16& st, short8& lo, short8& hi8) {
    u32 pk[8];
#pragma unroll
    for (int t2 = 0; t2 < 8; ++t2)
      asm("v_cvt_pk_bf16_f32 %0, %1, %2" : "=v"(pk[t2]) : "v"(st[2 * t2]), "v"(st[2 * t2 + 1]));
    u32 a0 = pk[0], a1 = pk[2]; asm("v_permlane32_swap_b32 %0, %1" : "+v"(a0), "+v"(a1));
    u32 a2 = pk[1], a3 = pk[3]; asm("v_permlane32_swap_b32 %0, %1" : "+v"(a2), "+v"(a3));
    u32 c0 = pk[4], c1 = pk[6]; asm("v_permlane32_swap_b32 %0, %1" : "+v"(c0), "+v"(c1));
    u32 c2 = pk[5], c3 = pk[7]; asm("v_permlane32_swap_b32 %0, %1" : "+v"(c2), "+v"(c3));
    union { u32 u[4]; short8 s; } f0, f1;
    f0.u[0] = a0; f0.u[1] = a2; f0.u[2] = a1; f0.u[3] = a3;
    f1.u[0] = c0; f1.u[1] = c2; f1.u[2] = c1; f1.u[3] = c3;
    lo = f0.s; hi8 = f1.s;
  };

  auto body64 = [&](int buf, bool mask2) {
    const char* kb = (const char*)&lK[g][buf][0] + lq * 128;
    const char* vb = (const char*)&lV[g][buf][0] + lq * 128;
    short8 kf0[4], kf1[4];
#pragma unroll
    for (int kk = 0; kk < 4; ++kk) {
      const int sl = ((2 * kk + hi) ^ swsl) << 4;
      kf0[kk] = *(const short8*)(kb + sl);
      kf1[kk] = *(const short8*)(kb + 4096 + sl);
    }
    f32x16 st0 = {}, st1 = {};
    __builtin_amdgcn_s_setprio(1);
#pragma unroll
    for (int kk = 0; kk < 4; ++kk)
      st0 = __builtin_amdgcn_mfma_f32_32x32x16_bf16(kf0[kk], qf[kk], st0, 0, 0, 0);
#pragma unroll
    for (int kk = 0; kk < 4; ++kk)
      st1 = __builtin_amdgcn_mfma_f32_32x32x16_bf16(kf1[kk], qf[kk], st1, 0, 0, 0);
    __builtin_amdgcn_s_setprio(0);

    short8 vfA[4], vfB[4];
#pragma unroll
    for (int ks = 0; ks < 4; ++ks) {
      const int sl = ((2 * ks + hi) ^ swsl) << 4;
      vfA[ks] = *(const short8*)(vb + sl);
      vfB[ks] = *(const short8*)(vb + 4096 + sl);
    }

    if (mask2) {
      const int qm = lq - hi * 4;
#pragma unroll
      for (int r = 0; r < 16; ++r) {
        const int t = (r & 3) + 8 * (r >> 2);
        if (t > qm) st1[r] = -3.0e38f;
      }
    }

    float a0 = max3f(st0[0], st0[1], st0[2]);
    float a1 = max3f(st0[3], st0[4], st0[5]);
    float a2 = max3f(st0[6], st0[7], st0[8]);
    float a3 = max3f(st0[9], st0[10], st0[11]);
    float a4 = max3f(st0[12], st0[13], st0[14]);
    float a5 = max3f(st0[15], st1[0], st1[1]);
    float a6 = max3f(st1[2], st1[3], st1[4]);
    float a7 = max3f(st1[5], st1[6], st1[7]);
    float a8 = max3f(st1[8], st1[9], st1[10]);
    float a9 = max3f(st1[11], st1[12], st1[13]);
    float a10 = fmaxf(st1[14], st1[15]);
    float b0 = max3f(a0, a1, a2);
    float b1 = max3f(a3, a4, a5);
    float b2 = max3f(a6, a7, a8);
    float b3 = max3f(a9, a10, b0);
    float pm = max3f(b1, b2, b3);
    pm = fmaxf(pm, __shfl_xor(pm, 32));

    if (!__all(pm <= m + 8.0f)) {        // defer-max (T13)
      const float mn = fmaxf(m, pm);
      const float alpha = __builtin_amdgcn_exp2f(m - mn);
      lsum *= alpha;
#pragma unroll
      for (int r = 0; r < 16; ++r) { oA[r] *= alpha; oB[r] *= alpha; }
      m = mn;
    }

#pragma unroll
    for (int r = 0; r < 16; ++r) st0[r] = __builtin_amdgcn_exp2f(st0[r] - m);
#pragma unroll
    for (int r = 0; r < 16; ++r) st1[r] = __builtin_amdgcn_exp2f(st1[r] - m);

    float s0 = (st0[0] + st0[1]) + (st0[2] + st0[3]);
    float s1 = (st0[4] + st0[5]) + (st0[6] + st0[7]);
    float s2 = (st0[8] + st0[9]) + (st0[10] + st0[11]);
    float s3 = (st0[12] + st0[13]) + (st0[14] + st0[15]);
    float s4 = (st1[0] + st1[1]) + (st1[2] + st1[3]);
    float s5 = (st1[4] + st1[5]) + (st1[6] + st1[7]);
    float s6 = (st1[8] + st1[9]) + (st1[10] + st1[11]);
    float s7 = (st1[12] + st1[13]) + (st1[14] + st1[15]);
    float rs = ((s0 + s1) + (s2 + s3)) + ((s4 + s5) + (s6 + s7));
    rs += __shfl_xor(rs, 32);
    lsum += rs;

    short8 pf0, pf1, pf2, pf3;
    pack16(st0, pf0, pf1);
    pack16(st1, pf2, pf3);

    __builtin_amdgcn_s_setprio(1);
    oA = __builtin_amdgcn_mfma_f32_32x32x16_bf16(vfA[0], pf0, oA, 0, 0, 0);
    oA = __builtin_amdgcn_mfma_f32_32x32x16_bf16(vfA[1], pf1, oA, 0, 0, 0);
    oA = __builtin_amdgcn_mfma_f32_32x32x16_bf16(vfA[2], pf2, oA, 0, 0, 0);
    oA = __builtin_amdgcn_mfma_f32_32x32x16_bf16(vfA[3], pf3, oA, 0, 0, 0);
    oB = __builtin_amdgcn_mfma_f32_32x32x16_bf16(vfB[0], pf0, oB, 0, 0, 0);
    oB = __builtin_amdgcn_mfma_f32_32x32x16_bf16(vfB[1], pf1, oB, 0, 0, 0);
    oB = __builtin_amdgcn_mfma_f32_32x32x16_bf16(vfB[2], pf2, oB, 0, 0, 0);
    oB = __builtin_amdgcn_mfma_f32_32x32x16_bf16(vfB[3], pf3, oB, 0, 0, 0);
    __builtin_amdgcn_s_setprio(0);
  };

  auto body32m = [&](int buf) {
    const char* kb = (const char*)&lK[g][buf][0] + lq * 128;
    const char* vb = (const char*)&lV[g][buf][0] + lq * 128;
    short8 kf0[4];
#pragma unroll
    for (int kk = 0; kk < 4; ++kk)
      kf0[kk] = *(const short8*)(kb + (((2 * kk + hi) ^ swsl) << 4));
    f32x16 st0 = {};
    __builtin_amdgcn_s_setprio(1);
#pragma unroll
    for (int kk = 0; kk < 4; ++kk)
      st0 = __builtin_amdgcn_mfma_f32_32x32x16_bf16(kf0[kk], qf[kk], st0, 0, 0, 0);
    __builtin_amdgcn_s_setprio(0);

    short8 vfA[2], vfB[2];
#pragma unroll
    for (int ks = 0; ks < 2; ++ks) {
      const int sl = ((2 * ks + hi) ^ swsl) << 4;
      vfA[ks] = *(const short8*)(vb + sl);
      vfB[ks] = *(const short8*)(vb + 4096 + sl);
    }

    const int qm = lq - hi * 4;
#pragma unroll
    for (int r = 0; r < 16; ++r) {
      const int t = (r & 3) + 8 * (r >> 2);
      if (t > qm) st0[r] = -3.0e38f;
    }
    float a0 = max3f(st0[0], st0[1], st0[2]);
    float a1 = max3f(st0[3], st0[4], st0[5]);
    float a2 = max3f(st0[6], st0[7], st0[8]);
    float a3 = max3f(st0[9], st0[10], st0[11]);
    float a4 = max3f(st0[12], st0[13], st0[14]);
    float b0 = max3f(a0, a1, a2);
    float b1 = max3f(a3, a4, st0[15]);
    float pm = fmaxf(b0, b1);
    pm = fmaxf(pm, __shfl_xor(pm, 32));
    if (!__all(pm <= m + 8.0f)) {
      const float mn = fmaxf(m, pm);
      const float alpha = __builtin_amdgcn_exp2f(m - mn);
      lsum *= alpha;
#pragma unroll
      for (int r = 0; r < 16; ++r) { oA[r] *= alpha; oB[r] *= alpha; }
      m = mn;
    }
#pragma unroll
    for (int r = 0; r < 16; ++r) st0[r] = __builtin_amdgcn_exp2f(st0[r] - m);
    float s0 = (st0[0] + st0[1]) + (st0[2] + st0[3]);
    float s1 = (st0[4] + st0[5]) + (st0[6] + st0[7]);
    float s2 = (st0[8] + st0[9]) + (st0[10] + st0[11]);
    float s3 = (st0[12] + st0[13]) + (st0[14] + st0[15]);
    float rs = (s0 + s1) + (s2 + s3);
    rs += __shfl_xor(rs, 32);
    lsum += rs;

    short8 pf0, pf1;
    pack16(st0, pf0, pf1);
    __builtin_amdgcn_s_setprio(1);
    oA = __builtin_amdgcn_mfma_f32_32x32x16_bf16(vfA[0], pf0, oA, 0, 0, 0);
    oA = __builtin_amdgcn_mfma_f32_32x32x16_bf16(vfA[1], pf1, oA, 0, 0, 0);
    oB = __builtin_amdgcn_mfma_f32_32x32x16_bf16(vfB[0], pf0, oB, 0, 0, 0);
    oB = __builtin_amdgcn_mfma_f32_32x32x16_bf16(vfB[1], pf1, oB, 0, 0, 0);
    __builtin_amdgcn_s_setprio(0);
  };

  // per-group counted-vmcnt schedule (validated R15)
  stage(0, g);
  if (NC > 1) stage(1, 2 + g);
  for (int i = 0; i < NC; ++i) {
    const int cabs = 2 * i + g;
    const int buf = i & 1;
    if (i + 1 < NC) asm volatile("s_waitcnt vmcnt(4)" ::: "memory");
    else            asm volatile("s_waitcnt vmcnt(0)" ::: "memory");
    __builtin_amdgcn_s_barrier();
    __builtin_amdgcn_sched_barrier(0);
    if (cabs < cdiag) body64(buf, false);
    else if (cabs == cdiag) { if (wl & 1) body64(buf, true); else body32m(buf); }
    __builtin_amdgcn_s_barrier();
    if (i + 2 < NC) stage(buf, 2 * (i + 2) + g);
  }

  // merge: group 1 deposits (O, m, l) in reused LDS; group 0 merges and stores.
  float* mergeO  = (float*)&lK[0][0][0];   // [r 0..31][wave 0..3][lane] = 32KB
  float* mergeML = (float*)&lV[0][0][0];   // [0..511] m, [512..1023] lsum
  if (g == 1) {
#pragma unroll
    for (int r = 0; r < 16; ++r) {
      mergeO[r * 256 + wl * 64 + l] = oA[r];
      mergeO[(16 + r) * 256 + wl * 64 + l] = oB[r];
    }
    mergeML[wl * 64 + l] = m;
    mergeML[512 + wl * 64 + l] = lsum;
  }
  __syncthreads();
  if (g == 0) {
    const float m1 = mergeML[wl * 64 + l];
    const float l1 = mergeML[512 + wl * 64 + l];
    const float M = fmaxf(m, m1);
    const float sc0 = __builtin_amdgcn_exp2f(m - M);
    const float sc1 = __builtin_amdgcn_exp2f(m1 - M);
    const float L = lsum * sc0 + l1 * sc1;
    const float rl = __builtin_amdgcn_rcpf(L);
    const float a0 = sc0 * rl, a1 = sc1 * rl;
    const int b = bh >> 4, h = bh & 15;
    u16* orow = AO + ((size_t)(b * 2048 + q)) * 1024 + h * 64;
#pragma unroll
    for (int g4 = 0; g4 < 4; ++g4) {
      float e[4], f[4];
#pragma unroll
      for (int t = 0; t < 4; ++t) {
        const int r = 4 * g4 + t;
        e[t] = oA[r] * a0 + mergeO[r * 256 + wl * 64 + l] * a1;
        f[t] = oB[r] * a0 + mergeO[(16 + r) * 256 + wl * 64 + l] * a1;
      }
      u32 w0, w1, w2, w3;
      asm("v_cvt_pk_bf16_f32 %0, %1, %2" : "=v"(w0) : "v"(e[0]), "v"(e[1]));
      asm("v_cvt_pk_bf16_f32 %0, %1, %2" : "=v"(w1) : "v"(e[2]), "v"(e[3]));
      asm("v_cvt_pk_bf16_f32 %0, %1, %2" : "=v"(w2) : "v"(f[0]), "v"(f[1]));
      asm("v_cvt_pk_bf16_f32 %0, %1, %2" : "=v"(w3) : "v"(f[2]), "v"(f[3]));
      uint2 uA; uA.x = w0; uA.y = w1;
      uint2 uB; uB.x = w2; uB.y = w3;
      *(uint2*)&orow[8 * g4 + 4 * hi] = uA;        // d = 8*g4+4hi .. +3
      *(uint2*)&orow[32 + 8 * g4 + 4 * hi] = uB;   // d+32
    }
  }
}

// ---------------- launch ----------------

extern "C" void kernel_launch(void* const* d_in, const int* in_sizes, int n_in,
                              void* d_out, int out_size, void* d_ws, size_t ws_size,
                              hipStream_t stream) {
  const float* hs = (const float*)d_in[0];
  const float* w1 = (const float*)d_in[1];
  const float* b1 = (const float*)d_in[2];
  const float* w2 = (const float*)d_in[3];
  const float* b2 = (const float*)d_in[4];
  float* out = (float*)d_out;

  char* ws = (char*)d_ws;
  u16* Xb  = (u16*)(ws);                    // [4096][1024] bf16   (8 MB)
  u16* W1t = (u16*)(ws + (8ull  << 20));    // [3072][1024] bf16   (6 MB)
  u16* W2t = (u16*)(ws + (14ull << 20));    // [1024][1024] bf16   (2 MB)
  u16* Qb  = (u16*)(ws + (16ull << 20));    // [B,H,S,D] bf16      (8 MB)
  u16* Kb  = (u16*)(ws + (24ull << 20));    // [B,H,S,D] bf16      (8 MB)
  u16* Vtb = (u16*)(ws + (32ull << 20));    // [B,H,D,S] bf16      (8 MB)
  u16* AO  = (u16*)(ws + (40ull << 20));    // [4096][1024] bf16   (8 MB)

  prepass<<<dim3(6144), dim3(256), 0, stream>>>(hs, Xb, w1, W1t, w2, W2t);
  gemm8w<0><<<dim3(24, 32), dim3(512), 0, stream>>>(Xb, W1t, b1, Qb, Kb, Vtb, nullptr);
  attn_fwd10<<<dim3(512), dim3(512), 0, stream>>>(Qb, Kb, Vtb, AO);
  gemm8w<1><<<dim3(8, 32), dim3(512), 0, stream>>>(AO, W2t, b2, nullptr, nullptr, nullptr, out);
}